// Round 10
// baseline (162.660 us; speedup 1.0000x reference)
//
#include <hip/hip_runtime.h>
#include <math.h>

// CTC-CRF NLL: mean_b( logZ_den(b) - logZ_num(b) ), B=16,T=2048,S=8,L=256.
//
// R9: one serial wave per CU + transposed LDS streams.
//   Grid 3B blocks x 128 thr:
//     role 0 (bid 0..B-1):   num-fwd,  wave0 only (t = 1..tm)
//     role 1 (bid B..2B-1):  num-bwd,  wave0 only (t = len-1..tm+1)
//     role 2 (bid 2B..3B-1): den fwd+bwd (2 waves) + in-block combine
//   Num blocks stage emissions TRANSPOSED: stream j holds float2 pairs
//   (2^em[t][j], 2^em[t][j+4]) contiguous in t -> each lane reads its 4
//   gathered streams as 2x ds_read_b128 per 4-step group (8 b128 vs 16 b64).
//   Cross-block combine: agent-scope atomics into ws + ticket; last of 3B
//   blocks computes all num dot-products, adds den, writes mean.

#define LOG2E 1.4426950408889634f
#define LN2   0.69314718055994531f
#define CTL_WSHL1  0x130            // DPP wave_shl:1 (lane63 -> 0)
#define CTL_WSHR1  0x138            // DPP wave_shr:1 (lane0  -> 0)
#define CTL_ROR(r) (0x120 + (r))    // DPP row_ror:r

#define AST(p, v) __hip_atomic_store((p), (v), __ATOMIC_RELAXED, __HIP_MEMORY_SCOPE_AGENT)
#define ALD(p)    __hip_atomic_load((p), __ATOMIC_RELAXED, __HIP_MEMORY_SCOPE_AGENT)

template <int CTRL>
__device__ __forceinline__ float fdpp(float x) {
    return __int_as_float(__builtin_amdgcn_update_dpp(
        0, __float_as_int(x), CTRL, 0xF, 0xF, true));
}
template <int CTRL>
__device__ __forceinline__ int idpp(int x) {
    return __builtin_amdgcn_update_dpp(0, x, CTRL, 0xF, 0xF, true);
}
__device__ __forceinline__ void cfence() { asm volatile("" ::: "memory"); }

__device__ __forceinline__ float fexp2(float x) {
#if __has_builtin(__builtin_amdgcn_exp2f)
    return __builtin_amdgcn_exp2f(x);
#else
    return exp2f(x);
#endif
}
__device__ __forceinline__ float flog2(float x) {
#if __has_builtin(__builtin_amdgcn_logf)
    return __builtin_amdgcn_logf(x);
#else
    return __log2f(x);
#endif
}
__device__ __forceinline__ float lse2(float a, float b) {   // log2(2^a+2^b)
    float m = fmaxf(a, b);
    float d = fminf(a, b) - m;
    return m + flog2(1.0f + fexp2(d));
}

struct NumC { float tee[4], txe[4], tex[4], txx[4]; };

// ---------------- forward numerator (R8 proven) ----------------
__device__ __forceinline__ void numf_step(const float2* p, float* E, float* X,
                                          float teeF, float txeF, const NumC& c) {
    float nbE = fdpp<CTL_WSHR1>(E[3]);
    float nbX = fdpp<CTL_WSHR1>(X[3]);
    float nE0 = p[0].x * fmaf(nbE,  teeF,     nbX  * txeF);
    float nE1 = p[1].x * fmaf(E[0], c.tee[1], X[0] * c.txe[1]);
    float nE2 = p[2].x * fmaf(E[1], c.tee[2], X[1] * c.txe[2]);
    float nE3 = p[3].x * fmaf(E[2], c.tee[3], X[2] * c.txe[3]);
    float nX0 = p[0].y * fmaf(E[0], c.tex[0], X[0] * c.txx[0]);
    float nX1 = p[1].y * fmaf(E[1], c.tex[1], X[1] * c.txx[1]);
    float nX2 = p[2].y * fmaf(E[2], c.tex[2], X[2] * c.txx[2]);
    float nX3 = p[3].y * fmaf(E[3], c.tex[3], X[3] * c.txx[3]);
    E[0] = nE0; E[1] = nE1; E[2] = nE2; E[3] = nE3;
    X[0] = nX0; X[1] = nX1; X[2] = nX2; X[3] = nX3;
}

__device__ __forceinline__ void numf_boundary(float* E, float* X, int& s,
                                              float& teeF, float& txeF,
                                              int lane, const NumC& c) {
    float m = fmaxf(fmaxf(fmaxf(E[0], E[1]), fmaxf(E[2], E[3])),
                    fmaxf(fmaxf(X[0], X[1]), fmaxf(X[2], X[3])));
    const bool live = (m > 0.0f);
    const int ex = live ? ((int)(__float_as_uint(m) >> 23) - 126) : 0;
    s += ex;
    const int bs = idpp<CTL_WSHR1>(s);
    if (!live) s = bs;
    int d = (lane == 0) ? 0 : (bs - s);
    const int extra = (d > 30) ? d : 0;
    s += extra; d -= extra;
    const float fsc = ldexpf(1.0f, -(ex + extra));
#pragma unroll
    for (int k = 0; k < 4; ++k) { E[k] *= fsc; X[k] *= fsc; }
    const float fs0 = (lane == 0) ? 0.0f : ldexpf(1.0f, d);
    teeF = c.tee[0] * fs0;
    txeF = c.txe[0] * fs0;
}

// ---------------- backward numerator (R8 proven) ----------------
__device__ __forceinline__ void numb_step(const float2* p, float* bE, float* bX,
                                          const float* tex, const float* txx,
                                          const float* teeN, const float* txeN,
                                          float teeN3F, float txeN3F) {
    float mm0 = p[0].x * bE[0];
    float mm1 = p[1].x * bE[1];
    float mm2 = p[2].x * bE[2];
    float mm3 = p[3].x * bE[3];
    float m10 = p[0].y * bX[0];
    float m11 = p[1].y * bX[1];
    float m12 = p[2].y * bX[2];
    float m13 = p[3].y * bX[3];
    float mup = fdpp<CTL_WSHL1>(mm0);        // lane+1's mm0; lane63 -> 0
    float nE0 = fmaf(tex[0], m10, teeN[0] * mm1);
    float nE1 = fmaf(tex[1], m11, teeN[1] * mm2);
    float nE2 = fmaf(tex[2], m12, teeN[2] * mm3);
    float nE3 = fmaf(tex[3], m13, teeN3F   * mup);
    float nX0 = fmaf(txx[0], m10, txeN[0] * mm1);
    float nX1 = fmaf(txx[1], m11, txeN[1] * mm2);
    float nX2 = fmaf(txx[2], m12, txeN[2] * mm3);
    float nX3 = fmaf(txx[3], m13, txeN3F   * mup);
    bE[0] = nE0; bE[1] = nE1; bE[2] = nE2; bE[3] = nE3;
    bX[0] = nX0; bX[1] = nX1; bX[2] = nX2; bX[3] = nX3;
}

__device__ __forceinline__ void numb_boundary(float* bE, float* bX, int& s,
                                              float& teeN3F, float& txeN3F,
                                              int lane, float teeN3, float txeN3) {
    float m = fmaxf(fmaxf(fmaxf(bE[0], bE[1]), fmaxf(bE[2], bE[3])),
                    fmaxf(fmaxf(bX[0], bX[1]), fmaxf(bX[2], bX[3])));
    const bool live = (m > 0.0f);
    const int ex = live ? ((int)(__float_as_uint(m) >> 23) - 126) : 0;
    s += ex;
    const int bs = idpp<CTL_WSHL1>(s);
    if (!live) s = bs;
    int d = (lane == 63) ? 0 : (bs - s);
    const int extra = (d > 30) ? d : 0;
    s += extra; d -= extra;
    const float fsc = ldexpf(1.0f, -(ex + extra));
#pragma unroll
    for (int k = 0; k < 4; ++k) { bE[k] *= fsc; bX[k] *= fsc; }
    const float fs = (lane == 63) ? 0.0f : ldexpf(1.0f, d);
    teeN3F = teeN3 * fs;
    txeN3F = txeN3 * fs;
}

// ---------------- 4-step group executors over float4 buffers ----------------
__device__ __forceinline__ void steps4_fwd(const float4 buf[4][2], float* E, float* X,
                                           float teeF, float txeF, const NumC& c) {
#pragma unroll
    for (int q = 0; q < 4; ++q) {
        float2 p[4];
#pragma unroll
        for (int k = 0; k < 4; ++k) {
            const float4 v = buf[k][q >> 1];
            p[k] = (q & 1) ? make_float2(v.z, v.w) : make_float2(v.x, v.y);
        }
        numf_step(p, E, X, teeF, txeF, c);
    }
}
__device__ __forceinline__ void steps4_bwd(const float4 buf[4][2], float* bE, float* bX,
                                           const float* tex, const float* txx,
                                           const float* teeN, const float* txeN,
                                           float teeN3F, float txeN3F) {
#pragma unroll
    for (int q = 0; q < 4; ++q) {            // t, t-1, t-2, t-3
        const int h = 1 - (q >> 1);
        float2 p[4];
#pragma unroll
        for (int k = 0; k < 4; ++k) {
            const float4 v = buf[k][h];
            p[k] = (q & 1) ? make_float2(v.x, v.y) : make_float2(v.z, v.w);
        }
        numb_step(p, bE, bX, tex, txx, teeN, txeN, teeN3F, txeN3F);
    }
}

// ---------------- denominator steps (R8 proven) ----------------
__device__ __forceinline__ float denf_step(float al, float emt, const float* Tr) {
    float v1 = fdpp<CTL_ROR(1)>(al);
    float v2 = fdpp<CTL_ROR(2)>(al);
    float v3 = fdpp<CTL_ROR(3)>(al);
    float v4 = fdpp<CTL_ROR(4)>(al);
    float v5 = fdpp<CTL_ROR(5)>(al);
    float v6 = fdpp<CTL_ROR(6)>(al);
    float v7 = fdpp<CTL_ROR(7)>(al);
    float q0 = fmaf(v1, Tr[1], al * Tr[0]);
    float q1 = fmaf(v3, Tr[3], v2 * Tr[2]);
    float q2 = fmaf(v5, Tr[5], v4 * Tr[4]);
    float q3 = fmaf(v7, Tr[7], v6 * Tr[6]);
    return ((q0 + q1) + (q2 + q3)) * emt;
}
__device__ __forceinline__ float denb_step(float al, float emt, const float* TrB) {
    float g  = al * emt;
    float v1 = fdpp<CTL_ROR(7)>(g);
    float v2 = fdpp<CTL_ROR(6)>(g);
    float v3 = fdpp<CTL_ROR(5)>(g);
    float v4 = fdpp<CTL_ROR(4)>(g);
    float v5 = fdpp<CTL_ROR(3)>(g);
    float v6 = fdpp<CTL_ROR(2)>(g);
    float v7 = fdpp<CTL_ROR(1)>(g);
    float q0 = fmaf(v1, TrB[1], g * TrB[0]);
    float q1 = fmaf(v3, TrB[3], v2 * TrB[2]);
    float q2 = fmaf(v5, TrB[5], v4 * TrB[4]);
    float q3 = fmaf(v7, TrB[7], v6 * TrB[6]);
    return (q0 + q1) + (q2 + q3);
}

extern "C" __global__ void __launch_bounds__(128)
crf_fused(const float* __restrict__ em, const float* __restrict__ trans,
          const float* __restrict__ bos, const float* __restrict__ eos,
          const int* __restrict__ lengths, const int* __restrict__ targets,
          const int* __restrict__ tlens,
          float* __restrict__ ws, float* __restrict__ out,
          int B, int T, int S, int L)
{
    extern __shared__ float sm[];
    const int bid  = blockIdx.x;
    const int tid  = threadIdx.x;
    const int lane = tid & 63;
    const int wv   = tid >> 6;
    const int half = S >> 1;                 // = 4
    const int role = bid / B;                // 0 num-fwd, 1 num-bwd, 2 den
    const int b    = bid % B;
    const float* gem = em + (size_t)b * T * S;
    const int len = lengths[b];
    const int tm  = (len - 1) >> 1;

    // ws map (floats): [0]=ticket(int); NF/NB: 576/batch (512 state + 64 scales)
    float* NF  = ws + 16 + (size_t)b * 576;
    float* NB  = ws + 16 + (size_t)B * 576 + (size_t)b * 576;
    float* DEN = ws + 16 + (size_t)(2 * B) * 576;
    int* ticket = (int*)ws;

    // ---------------- staging ----------------
    if (role < 2) {
        // transposed streams: float2 s2[j*T + t] = (2^em[t][j], 2^em[t][j+4])
        float2* s2 = (float2*)sm;
        for (int t = tid; t < T; t += 128) {
            const float4* gr = (const float4*)(gem + t * S);
            float4 a = gr[0], c4 = gr[1];
            s2[0 * T + t] = make_float2(fexp2(a.x * LOG2E), fexp2(c4.x * LOG2E));
            s2[1 * T + t] = make_float2(fexp2(a.y * LOG2E), fexp2(c4.y * LOG2E));
            s2[2 * T + t] = make_float2(fexp2(a.z * LOG2E), fexp2(c4.z * LOG2E));
            s2[3 * T + t] = make_float2(fexp2(a.w * LOG2E), fexp2(c4.w * LOG2E));
        }
    } else {
        // row-interleaved for den: sm[t*8 + 2j+h]
        for (int t = tid; t < T; t += 128) {
            const float4* gr = (const float4*)(gem + t * S);
            float4 a = gr[0], c4 = gr[1];
            float4 w0, w1;
            w0.x = fexp2(a.x * LOG2E); w0.y = fexp2(c4.x * LOG2E);
            w0.z = fexp2(a.y * LOG2E); w0.w = fexp2(c4.y * LOG2E);
            w1.x = fexp2(a.z * LOG2E); w1.y = fexp2(c4.z * LOG2E);
            w1.z = fexp2(a.w * LOG2E); w1.w = fexp2(c4.w * LOG2E);
            ((float4*)sm)[t * 2]     = w0;
            ((float4*)sm)[t * 2 + 1] = w1;
        }
    }
    __syncthreads();

    if (role == 0 && wv == 0) {
        // =================== NUMERATOR FORWARD ===================
        const float2* s2 = (const float2*)sm;
        const float4* s4 = (const float4*)sm;
        const int Th = T >> 1;
        const int u0 = lane * 4;
        int e[4], ep[4];
        const int base = b * L;
#pragma unroll
        for (int k = 0; k < 4; ++k) {
            int u = u0 + k;
            e[k] = targets[base + ((u < L) ? u : (L - 1))];
        }
        ep[0] = (u0 > 0) ? targets[base + u0 - 1] : e[0];
        ep[1] = e[0]; ep[2] = e[1]; ep[3] = e[2];
        NumC c;
#pragma unroll
        for (int k = 0; k < 4; ++k) {
            c.tee[k] = fexp2(trans[ep[k] * S + e[k]] * LOG2E);
            c.txe[k] = fexp2(trans[(ep[k] + half) * S + e[k]] * LOG2E);
            c.tex[k] = fexp2(trans[e[k] * S + e[k] + half] * LOG2E);
            c.txx[k] = fexp2(trans[(e[k] + half) * S + e[k] + half] * LOG2E);
        }
        float E[4] = {0.f,0.f,0.f,0.f}, X[4] = {0.f,0.f,0.f,0.f};
        int s = 0;
        if (lane == 0) E[0] = fexp2(bos[e[0]] * LOG2E) * s2[e[0] * T].x;
        float teeF = (lane == 0) ? 0.0f : c.tee[0];
        float txeF = (lane == 0) ? 0.0f : c.txe[0];

        int t0 = 1;
        while (t0 <= tm && (t0 & 1)) {       // align to even t0 (1 step)
            float2 p[4];
#pragma unroll
            for (int k = 0; k < 4; ++k) p[k] = s2[e[k] * T + t0];
            numf_step(p, E, X, teeF, txeF, c);
            ++t0;
        }
        float4 A[4][2], Bf[4][2];
        if (t0 + 7 <= tm) {
#pragma unroll
            for (int k = 0; k < 4; ++k) {
                A[k][0] = s4[e[k] * Th + (t0 >> 1)];
                A[k][1] = s4[e[k] * Th + ((t0 + 2) >> 1)];
            }
            cfence();
            while (t0 + 7 <= tm) {
#pragma unroll
                for (int k = 0; k < 4; ++k) {
                    Bf[k][0] = s4[e[k] * Th + ((t0 + 4) >> 1)];
                    Bf[k][1] = s4[e[k] * Th + ((t0 + 6) >> 1)];
                }
                cfence();
                steps4_fwd(A, E, X, teeF, txeF, c);
#pragma unroll
                for (int k = 0; k < 4; ++k) {      // t0+10 <= tm+3 < T: valid
                    A[k][0] = s4[e[k] * Th + ((t0 + 8) >> 1)];
                    A[k][1] = s4[e[k] * Th + ((t0 + 10) >> 1)];
                }
                cfence();
                steps4_fwd(Bf, E, X, teeF, txeF, c);
                numf_boundary(E, X, s, teeF, txeF, lane, c);
                t0 += 8;
            }
        }
        while (t0 <= tm) {                   // tail (< 8 steps)
            float2 p[4];
#pragma unroll
            for (int k = 0; k < 4; ++k) p[k] = s2[e[k] * T + t0];
            numf_step(p, E, X, teeF, txeF, c);
            ++t0;
        }
#pragma unroll
        for (int k = 0; k < 4; ++k) {
            AST(&NF[lane * 8 + k],     E[k]);
            AST(&NF[lane * 8 + 4 + k], X[k]);
        }
        AST(&NF[512 + lane], __int_as_float(s));
    } else if (role == 1 && wv == 0) {
        // =================== NUMERATOR BACKWARD ===================
        const float2* s2 = (const float2*)sm;
        const float4* s4 = (const float4*)sm;
        const int Th = T >> 1;
        const int u0 = lane * 4;
        int e[5];
        const int base = b * L;
#pragma unroll
        for (int k = 0; k < 5; ++k) {
            int u = u0 + k;
            e[k] = targets[base + ((u < L) ? u : (L - 1))];
        }
        float tex[4], txx[4], teeN[4], txeN[4];
#pragma unroll
        for (int k = 0; k < 4; ++k) {
            tex[k]  = fexp2(trans[e[k] * S + e[k] + half] * LOG2E);
            txx[k]  = fexp2(trans[(e[k] + half) * S + e[k] + half] * LOG2E);
            teeN[k] = fexp2(trans[e[k] * S + e[k + 1]] * LOG2E);
            txeN[k] = fexp2(trans[(e[k] + half) * S + e[k + 1]] * LOG2E);
        }
        if (lane == 63) { teeN[3] = 0.0f; txeN[3] = 0.0f; }
        float bE[4] = {0.f,0.f,0.f,0.f}, bX[4] = {0.f,0.f,0.f,0.f};
        const int uf = tlens[b] - 1;
        if (lane == (uf >> 2)) {
            const int kf = uf & 3;
            bE[kf] = fexp2(eos[e[kf]] * LOG2E);
            bX[kf] = fexp2(eos[e[kf] + half] * LOG2E);
        }
        int s = 0;
        float teeN3F = teeN[3], txeN3F = txeN[3];

        int t1 = len - 1;
        const int tlo = tm + 1;
        while (t1 >= tlo && !(t1 & 1)) {     // align to odd t1 (<=1 step)
            float2 p[4];
#pragma unroll
            for (int k = 0; k < 4; ++k) p[k] = s2[e[k] * T + t1];
            numb_step(p, bE, bX, tex, txx, teeN, txeN, teeN3F, txeN3F);
            --t1;
        }
        float4 A[4][2], Bf[4][2];
        if (t1 - 7 >= tlo) {
#pragma unroll
            for (int k = 0; k < 4; ++k) {
                A[k][0] = s4[e[k] * Th + ((t1 - 3) >> 1)];
                A[k][1] = s4[e[k] * Th + ((t1 - 1) >> 1)];
            }
            cfence();
            while (t1 - 7 >= tlo) {
#pragma unroll
                for (int k = 0; k < 4; ++k) {
                    Bf[k][0] = s4[e[k] * Th + ((t1 - 7) >> 1)];
                    Bf[k][1] = s4[e[k] * Th + ((t1 - 5) >> 1)];
                }
                cfence();
                steps4_bwd(A, bE, bX, tex, txx, teeN, txeN, teeN3F, txeN3F);
                const int ta = (t1 - 11 > 0) ? (t1 - 11) : 0;   // clamp: even
#pragma unroll
                for (int k = 0; k < 4; ++k) {
                    A[k][0] = s4[e[k] * Th + (ta >> 1)];
                    A[k][1] = s4[e[k] * Th + ((ta + 2) >> 1)];
                }
                cfence();
                steps4_bwd(Bf, bE, bX, tex, txx, teeN, txeN, teeN3F, txeN3F);
                numb_boundary(bE, bX, s, teeN3F, txeN3F, lane, teeN[3], txeN[3]);
                t1 -= 8;
            }
        }
        while (t1 >= tlo) {                  // tail
            float2 p[4];
#pragma unroll
            for (int k = 0; k < 4; ++k) p[k] = s2[e[k] * T + t1];
            numb_step(p, bE, bX, tex, txx, teeN, txeN, teeN3F, txeN3F);
            --t1;
        }
#pragma unroll
        for (int k = 0; k < 4; ++k) {
            AST(&NB[lane * 8 + k],     bE[k]);
            AST(&NB[lane * 8 + 4 + k], bX[k]);
        }
        AST(&NB[512 + lane], __int_as_float(s));
    } else if (role == 2) {
        // =================== DENOMINATOR (2 waves) ===================
        float* denF  = sm + T * 8;
        float* denB  = denF + 8;
        int*   denFs = (int*)(denB + 8);
        int*   denBs = denFs + 8;
        const int j  = lane & 7;
        const int jj = ((j & 3) << 1) + (j >> 2);
        if (wv == 0) {
            float Tr[8];
#pragma unroll
            for (int r = 0; r < 8; ++r)
                Tr[r] = fexp2(trans[((j - r) & 7) * S + j] * LOG2E);
            float al = fexp2(bos[j] * LOG2E) * sm[jj];
            int sc = 0;
            int t = 1;
            while (t + 3 <= tm) {
                float c0 = sm[t * 8 + jj];
                float c1 = sm[(t + 1) * 8 + jj];
                float c2 = sm[(t + 2) * 8 + jj];
                float c3 = sm[(t + 3) * 8 + jj];
                cfence();
                al = denf_step(al, c0, Tr);
                al = denf_step(al, c1, Tr);
                al = denf_step(al, c2, Tr);
                al = denf_step(al, c3, Tr);
                float mm = fmaxf(al, fdpp<CTL_ROR(4)>(al));
                mm = fmaxf(mm, fdpp<CTL_ROR(2)>(mm));
                mm = fmaxf(mm, fdpp<CTL_ROR(1)>(mm));
                const int ex = (int)(__float_as_uint(mm) >> 23) - 126;
                sc += ex;
                al = ldexpf(al, -ex);
                t += 4;
            }
            while (t <= tm) { al = denf_step(al, sm[t * 8 + jj], Tr); ++t; }
            if (lane < 8) { denF[j] = al; denFs[j] = sc; }
        } else {
            float TrB[8];
#pragma unroll
            for (int r = 0; r < 8; ++r)
                TrB[r] = fexp2(trans[j * S + ((j + r) & 7)] * LOG2E);
            float al = fexp2(eos[j] * LOG2E);
            int sc = 0;
            int t = len - 1;
            const int tlo = tm + 1;
            while (t - 3 >= tlo) {
                float c0 = sm[t * 8 + jj];
                float c1 = sm[(t - 1) * 8 + jj];
                float c2 = sm[(t - 2) * 8 + jj];
                float c3 = sm[(t - 3) * 8 + jj];
                cfence();
                al = denb_step(al, c0, TrB);
                al = denb_step(al, c1, TrB);
                al = denb_step(al, c2, TrB);
                al = denb_step(al, c3, TrB);
                float mm = fmaxf(al, fdpp<CTL_ROR(4)>(al));
                mm = fmaxf(mm, fdpp<CTL_ROR(2)>(mm));
                mm = fmaxf(mm, fdpp<CTL_ROR(1)>(mm));
                const int ex = (int)(__float_as_uint(mm) >> 23) - 126;
                sc += ex;
                al = ldexpf(al, -ex);
                t -= 4;
            }
            while (t >= tlo) { al = denb_step(al, sm[t * 8 + jj], TrB); --t; }
            if (lane < 8) { denB[j] = al; denBs[j] = sc; }
        }
        __syncthreads();
        if (wv == 0 && lane < 8) {
            const float a  = fmaxf(denF[j], 1e-37f);
            const float bb = fmaxf(denB[j], 1e-37f);
            float part = flog2(a) + flog2(bb) + (float)(denFs[j] + denBs[j]);
            part = lse2(part, __shfl_xor(part, 1, 64));
            part = lse2(part, __shfl_xor(part, 2, 64));
            part = lse2(part, __shfl_xor(part, 4, 64));
            if (j == 0) AST(&DEN[b], part);
        }
    }

    // ---------------- ticket + winner combine ----------------
    __syncthreads();                         // drains vmcnt for all waves
    int* wflag = (int*)sm;                   // emissions dead now
    if (tid == 0) {
        __threadfence();
        const int tk = atomicAdd(ticket, 1);
        wflag[0] = (tk == 3 * B - 1) ? 1 : 0;
    }
    __syncthreads();
    if (wflag[0] && tid < 64) {
        __threadfence();
        float acc = 0.0f;
        for (int bb2 = 0; bb2 < B; ++bb2) {
            const float* nf = ws + 16 + (size_t)bb2 * 576;
            const float* nb = ws + 16 + (size_t)B * 576 + (size_t)bb2 * 576;
            float v = 0.0f;
#pragma unroll
            for (int k = 0; k < 8; ++k)
                v = fmaf(ALD(&nf[lane * 8 + k]), ALD(&nb[lane * 8 + k]), v);
            const int st = __float_as_int(ALD(&nf[512 + lane]))
                         + __float_as_int(ALD(&nb[512 + lane]));
            float part = (v > 0.0f) ? (flog2(v) + (float)st) : -3.0e38f;
#pragma unroll
            for (int o = 1; o < 64; o <<= 1)
                part = lse2(part, __shfl_xor(part, o, 64));
            if (lane == 0) acc += ALD(&DEN[bb2]) - part;
        }
        if (lane == 0) out[0] = acc * (LN2 / (float)B);
    }
}

extern "C" void kernel_launch(void* const* d_in, const int* in_sizes, int n_in,
                              void* d_out, int out_size, void* d_ws, size_t ws_size,
                              hipStream_t stream)
{
    const float* em      = (const float*)d_in[0];
    const float* trans   = (const float*)d_in[1];
    const float* bos     = (const float*)d_in[2];
    const float* eos     = (const float*)d_in[3];
    const int*   lengths = (const int*)d_in[4];
    const int*   targets = (const int*)d_in[5];
    const int*   tlens   = (const int*)d_in[6];
    float* out = (float*)d_out;
    float* ws  = (float*)d_ws;

    const int B  = in_sizes[4];              // 16
    const int SS = in_sizes[1];              // 64
    int S = 1; while (S * S < SS) ++S;       // 8
    const int T = in_sizes[0] / (B * S);     // 2048
    const int L = in_sizes[5] / B;           // 256

    const size_t shmem = (size_t)(T * 8 + 64) * sizeof(float);

    (void)hipMemsetAsync(ws, 0, 64, stream); // ticket
    hipLaunchKernelGGL(crf_fused, dim3(3 * B), dim3(128), shmem, stream,
                       em, trans, bos, eos, lengths, targets, tlens,
                       ws, out, B, T, S, L);
}

// Round 12
// 161.059 us; speedup vs baseline: 1.0099x; 1.0099x over previous
//
#include <hip/hip_runtime.h>
#include <math.h>

// CTC-CRF NLL: mean_b( logZ_den(b) - logZ_num(b) ), B=16,T=2048,S=8,L=256.
//
// R11 = R9 (passed, absmax 0) + two changes:
//  1. __builtin_amdgcn_sched_barrier(0) pins group loads ahead of compute
//     (MIR-level; waitcnt insertion stays with the backend -> correct
//     fine-grained lgkmcnt(8) with next group's loads in flight). Raw-asm
//     ds_read (R10) is abandoned: the waitcnt pass can't see asm loads and
//     register consumers aren't ordered by a "memory"-clobber wait -> inf.
//  2. Transposed streams padded to pitch T+2 float2 (R10): the 4 streams
//     land on disjoint bank groups -> kills R9's 835k bank conflicts.

#define LOG2E 1.4426950408889634f
#define LN2   0.69314718055994531f
#define CTL_WSHL1  0x130            // DPP wave_shl:1 (lane63 -> 0)
#define CTL_WSHR1  0x138            // DPP wave_shr:1 (lane0  -> 0)
#define CTL_ROR(r) (0x120 + (r))    // DPP row_ror:r

#define AST(p, v) __hip_atomic_store((p), (v), __ATOMIC_RELAXED, __HIP_MEMORY_SCOPE_AGENT)
#define ALD(p)    __hip_atomic_load((p), __ATOMIC_RELAXED, __HIP_MEMORY_SCOPE_AGENT)

template <int CTRL>
__device__ __forceinline__ float fdpp(float x) {
    return __int_as_float(__builtin_amdgcn_update_dpp(
        0, __float_as_int(x), CTRL, 0xF, 0xF, true));
}
template <int CTRL>
__device__ __forceinline__ int idpp(int x) {
    return __builtin_amdgcn_update_dpp(0, x, CTRL, 0xF, 0xF, true);
}

__device__ __forceinline__ void pin() {      // scheduler fence (MIR-level)
#if __has_builtin(__builtin_amdgcn_sched_barrier)
    __builtin_amdgcn_sched_barrier(0);
#else
    asm volatile("" ::: "memory");
#endif
}

__device__ __forceinline__ float fexp2(float x) {
#if __has_builtin(__builtin_amdgcn_exp2f)
    return __builtin_amdgcn_exp2f(x);
#else
    return exp2f(x);
#endif
}
__device__ __forceinline__ float flog2(float x) {
#if __has_builtin(__builtin_amdgcn_logf)
    return __builtin_amdgcn_logf(x);
#else
    return __log2f(x);
#endif
}
__device__ __forceinline__ float lse2(float a, float b) {   // log2(2^a+2^b)
    float m = fmaxf(a, b);
    float d = fminf(a, b) - m;
    return m + flog2(1.0f + fexp2(d));
}

struct NumC { float tee[4], txe[4], tex[4], txx[4]; };

// ---------------- forward numerator (proven) ----------------
__device__ __forceinline__ void numf_step(const float2* p, float* E, float* X,
                                          float teeF, float txeF, const NumC& c) {
    float nbE = fdpp<CTL_WSHR1>(E[3]);
    float nbX = fdpp<CTL_WSHR1>(X[3]);
    float nE0 = p[0].x * fmaf(nbE,  teeF,     nbX  * txeF);
    float nE1 = p[1].x * fmaf(E[0], c.tee[1], X[0] * c.txe[1]);
    float nE2 = p[2].x * fmaf(E[1], c.tee[2], X[1] * c.txe[2]);
    float nE3 = p[3].x * fmaf(E[2], c.tee[3], X[2] * c.txe[3]);
    float nX0 = p[0].y * fmaf(E[0], c.tex[0], X[0] * c.txx[0]);
    float nX1 = p[1].y * fmaf(E[1], c.tex[1], X[1] * c.txx[1]);
    float nX2 = p[2].y * fmaf(E[2], c.tex[2], X[2] * c.txx[2]);
    float nX3 = p[3].y * fmaf(E[3], c.tex[3], X[3] * c.txx[3]);
    E[0] = nE0; E[1] = nE1; E[2] = nE2; E[3] = nE3;
    X[0] = nX0; X[1] = nX1; X[2] = nX2; X[3] = nX3;
}

__device__ __forceinline__ void numf_boundary(float* E, float* X, int& s,
                                              float& teeF, float& txeF,
                                              int lane, const NumC& c) {
    float m = fmaxf(fmaxf(fmaxf(E[0], E[1]), fmaxf(E[2], E[3])),
                    fmaxf(fmaxf(X[0], X[1]), fmaxf(X[2], X[3])));
    const bool live = (m > 0.0f);
    const int ex = live ? ((int)(__float_as_uint(m) >> 23) - 126) : 0;
    s += ex;
    const int bs = idpp<CTL_WSHR1>(s);
    if (!live) s = bs;
    int d = (lane == 0) ? 0 : (bs - s);
    const int extra = (d > 30) ? d : 0;
    s += extra; d -= extra;
    const float fsc = ldexpf(1.0f, -(ex + extra));
#pragma unroll
    for (int k = 0; k < 4; ++k) { E[k] *= fsc; X[k] *= fsc; }
    const float fs0 = (lane == 0) ? 0.0f : ldexpf(1.0f, d);
    teeF = c.tee[0] * fs0;
    txeF = c.txe[0] * fs0;
}

// ---------------- backward numerator (proven) ----------------
__device__ __forceinline__ void numb_step(const float2* p, float* bE, float* bX,
                                          const float* tex, const float* txx,
                                          const float* teeN, const float* txeN,
                                          float teeN3F, float txeN3F) {
    float mm0 = p[0].x * bE[0];
    float mm1 = p[1].x * bE[1];
    float mm2 = p[2].x * bE[2];
    float mm3 = p[3].x * bE[3];
    float m10 = p[0].y * bX[0];
    float m11 = p[1].y * bX[1];
    float m12 = p[2].y * bX[2];
    float m13 = p[3].y * bX[3];
    float mup = fdpp<CTL_WSHL1>(mm0);
    float nE0 = fmaf(tex[0], m10, teeN[0] * mm1);
    float nE1 = fmaf(tex[1], m11, teeN[1] * mm2);
    float nE2 = fmaf(tex[2], m12, teeN[2] * mm3);
    float nE3 = fmaf(tex[3], m13, teeN3F   * mup);
    float nX0 = fmaf(txx[0], m10, txeN[0] * mm1);
    float nX1 = fmaf(txx[1], m11, txeN[1] * mm2);
    float nX2 = fmaf(txx[2], m12, txeN[2] * mm3);
    float nX3 = fmaf(txx[3], m13, txeN3F   * mup);
    bE[0] = nE0; bE[1] = nE1; bE[2] = nE2; bE[3] = nE3;
    bX[0] = nX0; bX[1] = nX1; bX[2] = nX2; bX[3] = nX3;
}

__device__ __forceinline__ void numb_boundary(float* bE, float* bX, int& s,
                                              float& teeN3F, float& txeN3F,
                                              int lane, float teeN3, float txeN3) {
    float m = fmaxf(fmaxf(fmaxf(bE[0], bE[1]), fmaxf(bE[2], bE[3])),
                    fmaxf(fmaxf(bX[0], bX[1]), fmaxf(bX[2], bX[3])));
    const bool live = (m > 0.0f);
    const int ex = live ? ((int)(__float_as_uint(m) >> 23) - 126) : 0;
    s += ex;
    const int bs = idpp<CTL_WSHL1>(s);
    if (!live) s = bs;
    int d = (lane == 63) ? 0 : (bs - s);
    const int extra = (d > 30) ? d : 0;
    s += extra; d -= extra;
    const float fsc = ldexpf(1.0f, -(ex + extra));
#pragma unroll
    for (int k = 0; k < 4; ++k) { bE[k] *= fsc; bX[k] *= fsc; }
    const float fs = (lane == 63) ? 0.0f : ldexpf(1.0f, d);
    teeN3F = teeN3 * fs;
    txeN3F = txeN3 * fs;
}

// ---------------- 4-step executors over float4 buffers ----------------
__device__ __forceinline__ void steps4_fwd(const float4 buf[4][2], float* E, float* X,
                                           float teeF, float txeF, const NumC& c) {
#pragma unroll
    for (int q = 0; q < 4; ++q) {
        float2 p[4];
#pragma unroll
        for (int k = 0; k < 4; ++k) {
            const float4 v = buf[k][q >> 1];
            p[k] = (q & 1) ? make_float2(v.z, v.w) : make_float2(v.x, v.y);
        }
        numf_step(p, E, X, teeF, txeF, c);
    }
}
__device__ __forceinline__ void steps4_bwd(const float4 buf[4][2], float* bE, float* bX,
                                           const float* tex, const float* txx,
                                           const float* teeN, const float* txeN,
                                           float teeN3F, float txeN3F) {
#pragma unroll
    for (int q = 0; q < 4; ++q) {            // t, t-1, t-2, t-3 (t odd)
        const int h = 1 - (q >> 1);
        float2 p[4];
#pragma unroll
        for (int k = 0; k < 4; ++k) {
            const float4 v = buf[k][h];
            p[k] = (q & 1) ? make_float2(v.x, v.y) : make_float2(v.z, v.w);
        }
        numb_step(p, bE, bX, tex, txx, teeN, txeN, teeN3F, txeN3F);
    }
}

// ---------------- denominator steps (proven) ----------------
__device__ __forceinline__ float denf_step(float al, float emt, const float* Tr) {
    float v1 = fdpp<CTL_ROR(1)>(al);
    float v2 = fdpp<CTL_ROR(2)>(al);
    float v3 = fdpp<CTL_ROR(3)>(al);
    float v4 = fdpp<CTL_ROR(4)>(al);
    float v5 = fdpp<CTL_ROR(5)>(al);
    float v6 = fdpp<CTL_ROR(6)>(al);
    float v7 = fdpp<CTL_ROR(7)>(al);
    float q0 = fmaf(v1, Tr[1], al * Tr[0]);
    float q1 = fmaf(v3, Tr[3], v2 * Tr[2]);
    float q2 = fmaf(v5, Tr[5], v4 * Tr[4]);
    float q3 = fmaf(v7, Tr[7], v6 * Tr[6]);
    return ((q0 + q1) + (q2 + q3)) * emt;
}
__device__ __forceinline__ float denb_step(float al, float emt, const float* TrB) {
    float g  = al * emt;
    float v1 = fdpp<CTL_ROR(7)>(g);
    float v2 = fdpp<CTL_ROR(6)>(g);
    float v3 = fdpp<CTL_ROR(5)>(g);
    float v4 = fdpp<CTL_ROR(4)>(g);
    float v5 = fdpp<CTL_ROR(3)>(g);
    float v6 = fdpp<CTL_ROR(2)>(g);
    float v7 = fdpp<CTL_ROR(1)>(g);
    float q0 = fmaf(v1, TrB[1], g * TrB[0]);
    float q1 = fmaf(v3, TrB[3], v2 * TrB[2]);
    float q2 = fmaf(v5, TrB[5], v4 * TrB[4]);
    float q3 = fmaf(v7, TrB[7], v6 * TrB[6]);
    return (q0 + q1) + (q2 + q3);
}
__device__ __forceinline__ int den_renorm(float& al) {
    float mm = fmaxf(al, fdpp<CTL_ROR(4)>(al));
    mm = fmaxf(mm, fdpp<CTL_ROR(2)>(mm));
    mm = fmaxf(mm, fdpp<CTL_ROR(1)>(mm));
    const int ex = (int)(__float_as_uint(mm) >> 23) - 126;
    al = ldexpf(al, -ex);
    return ex;
}

extern "C" __global__ void __launch_bounds__(128)
crf_fused(const float* __restrict__ em, const float* __restrict__ trans,
          const float* __restrict__ bos, const float* __restrict__ eos,
          const int* __restrict__ lengths, const int* __restrict__ targets,
          const int* __restrict__ tlens,
          float* __restrict__ ws, float* __restrict__ out,
          int B, int T, int S, int L)
{
    extern __shared__ float sm[];
    const int bid  = blockIdx.x;
    const int tid  = threadIdx.x;
    const int lane = tid & 63;
    const int wv   = tid >> 6;
    const int half = S >> 1;                 // = 4
    const int role = bid / B;                // 0 num-fwd, 1 num-bwd, 2 den
    const int b    = bid % B;
    const float* gem = em + (size_t)b * T * S;
    const int len = lengths[b];
    const int tm  = (len - 1) >> 1;
    const int P2  = T + 2;                   // padded float2 pitch per stream
    const int Th2 = P2 >> 1;                 // float4 pitch per stream

    float* NF  = ws + 16 + (size_t)b * 576;
    float* NB  = ws + 16 + (size_t)B * 576 + (size_t)b * 576;
    float* DEN = ws + 16 + (size_t)(2 * B) * 576;
    int* ticket = (int*)ws;

    // ---------------- staging ----------------
    if (role < 2) {
        // padded transposed streams: s2[j*P2 + t] = (2^em[t][j], 2^em[t][j+4])
        float2* s2 = (float2*)sm;
        for (int t = tid; t < T; t += 128) {
            const float4* gr = (const float4*)(gem + t * S);
            float4 a = gr[0], c4 = gr[1];
            s2[0 * P2 + t] = make_float2(fexp2(a.x * LOG2E), fexp2(c4.x * LOG2E));
            s2[1 * P2 + t] = make_float2(fexp2(a.y * LOG2E), fexp2(c4.y * LOG2E));
            s2[2 * P2 + t] = make_float2(fexp2(a.z * LOG2E), fexp2(c4.z * LOG2E));
            s2[3 * P2 + t] = make_float2(fexp2(a.w * LOG2E), fexp2(c4.w * LOG2E));
        }
    } else {
        // row-interleaved for den: sm[t*8 + 2j+h]
        for (int t = tid; t < T; t += 128) {
            const float4* gr = (const float4*)(gem + t * S);
            float4 a = gr[0], c4 = gr[1];
            float4 w0, w1;
            w0.x = fexp2(a.x * LOG2E); w0.y = fexp2(c4.x * LOG2E);
            w0.z = fexp2(a.y * LOG2E); w0.w = fexp2(c4.y * LOG2E);
            w1.x = fexp2(a.z * LOG2E); w1.y = fexp2(c4.z * LOG2E);
            w1.z = fexp2(a.w * LOG2E); w1.w = fexp2(c4.w * LOG2E);
            ((float4*)sm)[t * 2]     = w0;
            ((float4*)sm)[t * 2 + 1] = w1;
        }
    }
    __syncthreads();

    if (role == 0 && wv == 0) {
        // =================== NUMERATOR FORWARD: t = 1..tm ===================
        const float2* s2 = (const float2*)sm;
        const float4* s4 = (const float4*)sm;
        const int u0 = lane * 4;
        int e[4], ep[4];
        const int base = b * L;
#pragma unroll
        for (int k = 0; k < 4; ++k) {
            int u = u0 + k;
            e[k] = targets[base + ((u < L) ? u : (L - 1))];
        }
        ep[0] = (u0 > 0) ? targets[base + u0 - 1] : e[0];
        ep[1] = e[0]; ep[2] = e[1]; ep[3] = e[2];
        NumC c;
#pragma unroll
        for (int k = 0; k < 4; ++k) {
            c.tee[k] = fexp2(trans[ep[k] * S + e[k]] * LOG2E);
            c.txe[k] = fexp2(trans[(ep[k] + half) * S + e[k]] * LOG2E);
            c.tex[k] = fexp2(trans[e[k] * S + e[k] + half] * LOG2E);
            c.txx[k] = fexp2(trans[(e[k] + half) * S + e[k] + half] * LOG2E);
        }
        float E[4] = {0.f,0.f,0.f,0.f}, X[4] = {0.f,0.f,0.f,0.f};
        int s = 0;
        if (lane == 0) E[0] = fexp2(bos[e[0]] * LOG2E) * s2[e[0] * P2].x;
        float teeF = (lane == 0) ? 0.0f : c.tee[0];
        float txeF = (lane == 0) ? 0.0f : c.txe[0];

        int t0 = 1;
        while (t0 <= tm && (t0 & 1)) {       // align to even t0
            float2 p[4];
#pragma unroll
            for (int k = 0; k < 4; ++k) p[k] = s2[e[k] * P2 + t0];
            numf_step(p, E, X, teeF, txeF, c);
            ++t0;
        }
        if (t0 + 7 <= tm) {
            float4 A[4][2], Bf[4][2];
#pragma unroll
            for (int k = 0; k < 4; ++k) {
                A[k][0] = s4[e[k] * Th2 + (t0 >> 1)];
                A[k][1] = s4[e[k] * Th2 + ((t0 + 2) >> 1)];
            }
            pin();
            while (t0 + 7 <= tm) {
#pragma unroll
                for (int k = 0; k < 4; ++k) {
                    Bf[k][0] = s4[e[k] * Th2 + ((t0 + 4) >> 1)];
                    Bf[k][1] = s4[e[k] * Th2 + ((t0 + 6) >> 1)];
                }
                pin();
                steps4_fwd(A, E, X, teeF, txeF, c);
#pragma unroll
                for (int k = 0; k < 4; ++k) {      // t0+10 <= tm+3 < T: valid
                    A[k][0] = s4[e[k] * Th2 + ((t0 + 8) >> 1)];
                    A[k][1] = s4[e[k] * Th2 + ((t0 + 10) >> 1)];
                }
                pin();
                steps4_fwd(Bf, E, X, teeF, txeF, c);
                numf_boundary(E, X, s, teeF, txeF, lane, c);
                t0 += 8;
            }
        }
        while (t0 <= tm) {                   // tail
            float2 p[4];
#pragma unroll
            for (int k = 0; k < 4; ++k) p[k] = s2[e[k] * P2 + t0];
            numf_step(p, E, X, teeF, txeF, c);
            ++t0;
        }
#pragma unroll
        for (int k = 0; k < 4; ++k) {
            AST(&NF[lane * 8 + k],     E[k]);
            AST(&NF[lane * 8 + 4 + k], X[k]);
        }
        AST(&NF[512 + lane], __int_as_float(s));
    } else if (role == 1 && wv == 0) {
        // =================== NUMERATOR BACKWARD: t = len-1..tm+1 ===========
        const float2* s2 = (const float2*)sm;
        const float4* s4 = (const float4*)sm;
        const int u0 = lane * 4;
        int e[5];
        const int base = b * L;
#pragma unroll
        for (int k = 0; k < 5; ++k) {
            int u = u0 + k;
            e[k] = targets[base + ((u < L) ? u : (L - 1))];
        }
        float tex[4], txx[4], teeN[4], txeN[4];
#pragma unroll
        for (int k = 0; k < 4; ++k) {
            tex[k]  = fexp2(trans[e[k] * S + e[k] + half] * LOG2E);
            txx[k]  = fexp2(trans[(e[k] + half) * S + e[k] + half] * LOG2E);
            teeN[k] = fexp2(trans[e[k] * S + e[k + 1]] * LOG2E);
            txeN[k] = fexp2(trans[(e[k] + half) * S + e[k + 1]] * LOG2E);
        }
        if (lane == 63) { teeN[3] = 0.0f; txeN[3] = 0.0f; }
        float bE[4] = {0.f,0.f,0.f,0.f}, bX[4] = {0.f,0.f,0.f,0.f};
        const int uf = tlens[b] - 1;
        if (lane == (uf >> 2)) {
            const int kf = uf & 3;
            bE[kf] = fexp2(eos[e[kf]] * LOG2E);
            bX[kf] = fexp2(eos[e[kf] + half] * LOG2E);
        }
        int s = 0;
        float teeN3F = teeN[3], txeN3F = txeN[3];

        int t1 = len - 1;
        const int tlo = tm + 1;
        while (t1 >= tlo && !(t1 & 1)) {     // align to odd t1
            float2 p[4];
#pragma unroll
            for (int k = 0; k < 4; ++k) p[k] = s2[e[k] * P2 + t1];
            numb_step(p, bE, bX, tex, txx, teeN, txeN, teeN3F, txeN3F);
            --t1;
        }
        if (t1 - 7 >= tlo) {
            float4 A[4][2], Bf[4][2];
#pragma unroll
            for (int k = 0; k < 4; ++k) {
                A[k][0] = s4[e[k] * Th2 + ((t1 - 3) >> 1)];
                A[k][1] = s4[e[k] * Th2 + ((t1 - 1) >> 1)];
            }
            pin();
            while (t1 - 7 >= tlo) {
#pragma unroll
                for (int k = 0; k < 4; ++k) {
                    Bf[k][0] = s4[e[k] * Th2 + ((t1 - 7) >> 1)];
                    Bf[k][1] = s4[e[k] * Th2 + ((t1 - 5) >> 1)];
                }
                pin();
                steps4_bwd(A, bE, bX, tex, txx, teeN, txeN, teeN3F, txeN3F);
                const int ta = (t1 - 11 > 0) ? (t1 - 11) : 0;   // even; >=0
#pragma unroll
                for (int k = 0; k < 4; ++k) {
                    A[k][0] = s4[e[k] * Th2 + (ta >> 1)];
                    A[k][1] = s4[e[k] * Th2 + ((ta + 2) >> 1)];
                }
                pin();
                steps4_bwd(Bf, bE, bX, tex, txx, teeN, txeN, teeN3F, txeN3F);
                numb_boundary(bE, bX, s, teeN3F, txeN3F, lane, teeN[3], txeN[3]);
                t1 -= 8;
            }
        }
        while (t1 >= tlo) {                  // tail
            float2 p[4];
#pragma unroll
            for (int k = 0; k < 4; ++k) p[k] = s2[e[k] * P2 + t1];
            numb_step(p, bE, bX, tex, txx, teeN, txeN, teeN3F, txeN3F);
            --t1;
        }
#pragma unroll
        for (int k = 0; k < 4; ++k) {
            AST(&NB[lane * 8 + k],     bE[k]);
            AST(&NB[lane * 8 + 4 + k], bX[k]);
        }
        AST(&NB[512 + lane], __int_as_float(s));
    } else if (role == 2) {
        // =================== DENOMINATOR (2 waves) ===================
        float* denF  = sm + T * 8 + 16;
        float* denB  = denF + 8;
        int*   denFs = (int*)(denB + 8);
        int*   denBs = denFs + 8;
        const int j  = lane & 7;
        const int jj = ((j & 3) << 1) + (j >> 2);
        if (wv == 0) {
            float Tr[8];
#pragma unroll
            for (int r = 0; r < 8; ++r)
                Tr[r] = fexp2(trans[((j - r) & 7) * S + j] * LOG2E);
            float al = fexp2(bos[j] * LOG2E) * sm[jj];
            int sc = 0;
            int t = 1;
            while (t + 3 <= tm) {
                float c0 = sm[t * 8 + jj];
                float c1 = sm[(t + 1) * 8 + jj];
                float c2 = sm[(t + 2) * 8 + jj];
                float c3 = sm[(t + 3) * 8 + jj];
                pin();
                al = denf_step(al, c0, Tr);
                al = denf_step(al, c1, Tr);
                al = denf_step(al, c2, Tr);
                al = denf_step(al, c3, Tr);
                sc += den_renorm(al);
                t += 4;
            }
            while (t <= tm) { al = denf_step(al, sm[t * 8 + jj], Tr); ++t; }
            if (lane < 8) { denF[j] = al; denFs[j] = sc; }
        } else {
            float TrB[8];
#pragma unroll
            for (int r = 0; r < 8; ++r)
                TrB[r] = fexp2(trans[j * S + ((j + r) & 7)] * LOG2E);
            float al = fexp2(eos[j] * LOG2E);
            int sc = 0;
            int t = len - 1;
            const int tlo = tm + 1;
            while (t - 3 >= tlo) {
                float c0 = sm[t * 8 + jj];
                float c1 = sm[(t - 1) * 8 + jj];
                float c2 = sm[(t - 2) * 8 + jj];
                float c3 = sm[(t - 3) * 8 + jj];
                pin();
                al = denb_step(al, c0, TrB);
                al = denb_step(al, c1, TrB);
                al = denb_step(al, c2, TrB);
                al = denb_step(al, c3, TrB);
                sc += den_renorm(al);
                t -= 4;
            }
            while (t >= tlo) { al = denb_step(al, sm[t * 8 + jj], TrB); --t; }
            if (lane < 8) { denB[j] = al; denBs[j] = sc; }
        }
        __syncthreads();
        if (wv == 0 && lane < 8) {
            const float a  = fmaxf(denF[j], 1e-37f);
            const float bb = fmaxf(denB[j], 1e-37f);
            float part = flog2(a) + flog2(bb) + (float)(denFs[j] + denBs[j]);
            part = lse2(part, __shfl_xor(part, 1, 64));
            part = lse2(part, __shfl_xor(part, 2, 64));
            part = lse2(part, __shfl_xor(part, 4, 64));
            if (j == 0) AST(&DEN[b], part);
        }
    }

    // ---------------- ticket + winner combine ----------------
    __syncthreads();
    int* wflag = (int*)sm;
    if (tid == 0) {
        __threadfence();
        const int tk = atomicAdd(ticket, 1);
        wflag[0] = (tk == 3 * B - 1) ? 1 : 0;
    }
    __syncthreads();
    if (wflag[0] && tid < 64) {
        __threadfence();
        float acc = 0.0f;
        for (int bb2 = 0; bb2 < B; ++bb2) {
            const float* nf = ws + 16 + (size_t)bb2 * 576;
            const float* nb = ws + 16 + (size_t)B * 576 + (size_t)bb2 * 576;
            float v = 0.0f;
#pragma unroll
            for (int k = 0; k < 8; ++k)
                v = fmaf(ALD(&nf[lane * 8 + k]), ALD(&nb[lane * 8 + k]), v);
            const int st = __float_as_int(ALD(&nf[512 + lane]))
                         + __float_as_int(ALD(&nb[512 + lane]));
            float part = (v > 0.0f) ? (flog2(v) + (float)st) : -3.0e38f;
#pragma unroll
            for (int o = 1; o < 64; o <<= 1)
                part = lse2(part, __shfl_xor(part, o, 64));
            if (lane == 0) acc += ALD(&DEN[bb2]) - part;
        }
        if (lane == 0) out[0] = acc * (LN2 / (float)B);
    }
}

extern "C" void kernel_launch(void* const* d_in, const int* in_sizes, int n_in,
                              void* d_out, int out_size, void* d_ws, size_t ws_size,
                              hipStream_t stream)
{
    const float* em      = (const float*)d_in[0];
    const float* trans   = (const float*)d_in[1];
    const float* bos     = (const float*)d_in[2];
    const float* eos     = (const float*)d_in[3];
    const int*   lengths = (const int*)d_in[4];
    const int*   targets = (const int*)d_in[5];
    const int*   tlens   = (const int*)d_in[6];
    float* out = (float*)d_out;
    float* ws  = (float*)d_ws;

    const int B  = in_sizes[4];              // 16
    const int SS = in_sizes[1];              // 64
    int S = 1; while (S * S < SS) ++S;       // 8
    const int T = in_sizes[0] / (B * S);     // 2048
    const int L = in_sizes[5] / B;           // 256

    // padded streams need 8*(T+2) floats; den needs T*8 + small scratch
    const size_t shmem = (size_t)(T * 8 + 80) * sizeof(float);

    (void)hipMemsetAsync(ws, 0, 64, stream); // ticket
    hipLaunchKernelGGL(crf_fused, dim3(3 * B), dim3(128), shmem, stream,
                       em, trans, bos, eos, lengths, targets, tlens,
                       ws, out, B, T, S, L);
}